// Round 1
// baseline (820.740 us; speedup 1.0000x reference)
//
#include <hip/hip_runtime.h>
#include <math.h>

#define T_TOT 65536   // N*L = 64*1024
#define C_DIM 256
#define M_DIM 128
#define SHRINKF 0.0025f
#define EPSF 1e-12f

// ---------------- block reductions (256 threads = 4 waves) ----------------
__device__ inline float bredMax(float v, volatile float* red, int tid) {
    #pragma unroll
    for (int o = 32; o > 0; o >>= 1) v = fmaxf(v, __shfl_down(v, o, 64));
    __syncthreads();
    if ((tid & 63) == 0) red[tid >> 6] = v;
    __syncthreads();
    return fmaxf(fmaxf(red[0], red[1]), fmaxf(red[2], red[3]));
}

__device__ inline float bredSum(float v, volatile float* red, int tid) {
    #pragma unroll
    for (int o = 32; o > 0; o >>= 1) v += __shfl_down(v, o, 64);
    __syncthreads();
    if ((tid & 63) == 0) red[tid >> 6] = v;
    __syncthreads();
    return red[0] + red[1] + red[2] + red[3];
}

// ---------------- K1: S_u[m,t] = dot(mem[m,:], q[t,:]) ----------------
// grid = T/32 blocks, 256 threads. t-tile=32 staged in LDS; mem rows stream
// from global (128KB total, L2-resident, wave-uniform addresses).
__global__ __launch_bounds__(256) void k_scores_u(const float* __restrict__ q,
                                                  const float* __restrict__ mem,
                                                  float* __restrict__ S) {
    __shared__ float4 ldsQ[32 * 65];   // row stride 65 float4s (pad) = 33.3KB
    int tid = threadIdx.x;
    int t0 = blockIdx.x * 32;
    const float4* q4 = (const float4*)(q + (size_t)t0 * C_DIM);
    #pragma unroll
    for (int k = 0; k < 8; ++k) {
        int idx = k * 256 + tid;            // 0..2047 = 32t x 64c4
        int t = idx >> 6, c4 = idx & 63;
        ldsQ[t * 65 + c4] = q4[t * 64 + c4];
    }
    __syncthreads();
    int t = tid & 31, mg = tid >> 5;        // 32 t x 8 m-groups
    const float4* m4 = (const float4*)mem;
    const float4* qrow = ldsQ + t * 65;
    for (int mi = 0; mi < 16; ++mi) {
        int m = mg * 16 + mi;
        const float4* mrow = m4 + m * 64;
        float acc = 0.f;
        #pragma unroll 8
        for (int c4 = 0; c4 < 64; ++c4) {
            float4 a = qrow[c4], b = mrow[c4];
            acc += a.x * b.x + a.y * b.y + a.z * b.z + a.w * b.w;
        }
        S[(size_t)m * T_TOT + t0 + t] = acc;  // coalesced over t
    }
}

// ---------------- K2: per-m softmax stats + sparse add_mem ----------------
// One block per m (128 blocks). Softmax over 65536 cols; hard-shrink leaves
// <400 survivors (sum(a)=1, each > 0.0025). Compact survivors to LDS, then
// add_mem[m,c] = sum_j w_j * q[t_j, c].
__global__ __launch_bounds__(256) void k_update(const float* __restrict__ S,
                                                const float* __restrict__ q,
                                                float* __restrict__ add_mem) {
    __shared__ float red[4];
    __shared__ int   ldsT[2048];
    __shared__ float ldsH[2048];
    __shared__ int   cnt;
    int m = blockIdx.x, tid = threadIdx.x;
    if (tid == 0) cnt = 0;
    const float4* row4 = (const float4*)(S + (size_t)m * T_TOT);

    // pass 1: row max
    float mx = -3e38f;
    for (int i = tid; i < T_TOT / 4; i += 256) {
        float4 v = row4[i];
        mx = fmaxf(fmaxf(fmaxf(mx, v.x), fmaxf(v.y, v.z)), v.w);
    }
    mx = bredMax(mx, red, tid);

    // pass 2: Z
    float z = 0.f;
    for (int i = tid; i < T_TOT / 4; i += 256) {
        float4 v = row4[i];
        z += __expf(v.x - mx) + __expf(v.y - mx) + __expf(v.z - mx) + __expf(v.w - mx);
    }
    z = bredSum(z, red, tid);
    float invZ = 1.f / z;

    // pass 3: hard-shrink survivors + L1
    float l1 = 0.f;
    for (int i = tid; i < T_TOT / 4; i += 256) {
        float4 v = row4[i];
        float av[4] = {v.x, v.y, v.z, v.w};
        #pragma unroll
        for (int j = 0; j < 4; ++j) {
            float a = __expf(av[j] - mx) * invZ;
            if (a > SHRINKF) {
                float d = a - SHRINKF;
                float h = d * a / (d + EPSF);   // relu(d)*a/(|d|+eps), d>0
                int p = atomicAdd(&cnt, 1);
                if (p < 2048) { ldsT[p] = i * 4 + j; ldsH[p] = h; }
                l1 += h;
            }
        }
    }
    l1 = bredSum(l1, red, tid);   // barriers inside publish ldsT/ldsH/cnt
    float invL1 = 1.f / fmaxf(l1, EPSF);

    // phase B: weighted gather of q rows
    int n = min(cnt, 2048);
    float acc = 0.f;
    for (int j = 0; j < n; ++j)
        acc += ldsH[j] * q[(size_t)ldsT[j] * C_DIM + tid];
    add_mem[m * C_DIM + tid] = acc * invL1;
}

// ---------------- K3: gate + new_mem ----------------
// new_mem[m,c] = (1-g)*mem + g*add_mem, g = sigmoid(mem@U_w.T + U_b + add_mem@W_w.T + W_b)
__global__ __launch_bounds__(256) void k_gate(const float* __restrict__ mem,
                                              const float* __restrict__ add_mem,
                                              const float* __restrict__ U_w,
                                              const float* __restrict__ U_b,
                                              const float* __restrict__ W_w,
                                              const float* __restrict__ W_b,
                                              float* __restrict__ new_mem) {
    __shared__ float ldsM[256], ldsA[256];
    int m = blockIdx.x, c = threadIdx.x;
    ldsM[c] = mem[m * C_DIM + c];
    ldsA[c] = add_mem[m * C_DIM + c];
    __syncthreads();
    float acc = U_b[c] + W_b[c];
    const float4* uw = (const float4*)(U_w + (size_t)c * C_DIM);
    const float4* ww = (const float4*)(W_w + (size_t)c * C_DIM);
    const float4* lm = (const float4*)ldsM;
    const float4* la = (const float4*)ldsA;
    #pragma unroll 8
    for (int k = 0; k < 64; ++k) {
        float4 a = lm[k], u = uw[k];
        acc += a.x * u.x + a.y * u.y + a.z * u.z + a.w * u.w;
        float4 b = la[k], w = ww[k];
        acc += b.x * w.x + b.y * w.y + b.z * w.z + b.w * w.w;
    }
    float g = 1.f / (1.f + __expf(-acc));
    new_mem[m * C_DIM + c] = (1.f - g) * ldsM[c] + g * ldsA[c];
}

// ---------------- K4: fused read stage ----------------
// Per 32-t tile: scores q@nm^T -> softmax over 128 m -> hsr -> L1 norm
// -> attn out; PV: out[:,256:512] = w @ nm; out[:,0:256] = q.
__global__ __launch_bounds__(256) void k_read(const float* __restrict__ q,
                                              const float* __restrict__ nm,
                                              float* __restrict__ out,
                                              float* __restrict__ attn) {
    __shared__ float ldsQ[32 * 260];   // padded stride 260 floats
    __shared__ float ldsW[32 * 132];   // scores -> weights, stride 132
    __shared__ float red[256];
    __shared__ float redA[32], redB[32];
    int tid = threadIdx.x;
    int t0 = blockIdx.x * 32;

    {   // stage q tile
        const float4* q4 = (const float4*)(q + (size_t)t0 * C_DIM);
        float4* lq4 = (float4*)ldsQ;
        #pragma unroll
        for (int k = 0; k < 8; ++k) {
            int idx = k * 256 + tid;
            int t = idx >> 6, c4 = idx & 63;
            lq4[t * 65 + c4] = q4[t * 64 + c4];
        }
    }
    __syncthreads();
    int t = tid & 31, mg = tid >> 5;   // 32 t x 8 m-groups of 16

    // phase 1: scores
    {
        const float4* lq = ((const float4*)ldsQ) + t * 65;
        const float4* nm4 = (const float4*)nm;
        for (int mi = 0; mi < 16; ++mi) {
            int m = mg * 16 + mi;
            const float4* nr = nm4 + m * 64;
            float acc = 0.f;
            #pragma unroll 8
            for (int c4 = 0; c4 < 64; ++c4) {
                float4 a = lq[c4], b = nr[c4];
                acc += a.x * b.x + a.y * b.y + a.z * b.z + a.w * b.w;
            }
            ldsW[t * 132 + m] = acc;
        }
    }
    // phase 2: softmax over m + hsr + L1 norm (partials per (t,mg))
    float pmax = -3e38f;
    for (int mi = 0; mi < 16; ++mi) pmax = fmaxf(pmax, ldsW[t * 132 + mg * 16 + mi]);
    red[t * 8 + mg] = pmax;
    __syncthreads();
    if (tid < 32) {
        float v = red[tid * 8];
        #pragma unroll
        for (int j = 1; j < 8; ++j) v = fmaxf(v, red[tid * 8 + j]);
        redA[tid] = v;
    }
    __syncthreads();
    float mx = redA[t];
    float pz = 0.f;
    for (int mi = 0; mi < 16; ++mi) pz += __expf(ldsW[t * 132 + mg * 16 + mi] - mx);
    red[t * 8 + mg] = pz;
    __syncthreads();
    if (tid < 32) {
        float v = 0.f;
        #pragma unroll
        for (int j = 0; j < 8; ++j) v += red[tid * 8 + j];
        redB[tid] = 1.f / v;
    }
    __syncthreads();
    float invZ = redB[t];
    float pl = 0.f;
    for (int mi = 0; mi < 16; ++mi) {
        int o = t * 132 + mg * 16 + mi;
        float a = __expf(ldsW[o] - mx) * invZ;
        float d = a - SHRINKF;
        float h = d > 0.f ? d * a / (d + EPSF) : 0.f;
        ldsW[o] = h;
        pl += h;
    }
    red[t * 8 + mg] = pl;
    __syncthreads();
    if (tid < 32) {
        float v = 0.f;
        #pragma unroll
        for (int j = 0; j < 8; ++j) v += red[tid * 8 + j];
        redA[tid] = 1.f / fmaxf(v, EPSF);
    }
    __syncthreads();
    float invL1 = redA[t];
    for (int mi = 0; mi < 16; ++mi) ldsW[t * 132 + mg * 16 + mi] *= invL1;
    __syncthreads();

    // attn out (coalesced)
    #pragma unroll
    for (int k = 0; k < 16; ++k) {
        int idx = k * 256 + tid;
        int tt = idx >> 7, m = idx & 127;
        attn[(size_t)(t0 + tt) * M_DIM + m] = ldsW[tt * 132 + m];
    }
    // q passthrough (coalesced)
    #pragma unroll
    for (int k = 0; k < 32; ++k) {
        int idx = k * 256 + tid;
        int tt = idx >> 8, c = idx & 255;
        out[(size_t)(t0 + tt) * 512 + c] = ldsQ[tt * 260 + c];
    }
    // phase 3: PV — thread owns column c, 32 accumulators over t
    {
        int c = tid;
        float acc[32];
        #pragma unroll
        for (int i = 0; i < 32; ++i) acc[i] = 0.f;
        for (int m4 = 0; m4 < 32; ++m4) {
            float n0 = nm[(size_t)(m4 * 4 + 0) * C_DIM + c];
            float n1 = nm[(size_t)(m4 * 4 + 1) * C_DIM + c];
            float n2 = nm[(size_t)(m4 * 4 + 2) * C_DIM + c];
            float n3 = nm[(size_t)(m4 * 4 + 3) * C_DIM + c];
            #pragma unroll
            for (int tt = 0; tt < 32; ++tt) {
                const float4 w4 = *((const float4*)(ldsW + tt * 132 + m4 * 4));
                acc[tt] += w4.x * n0 + w4.y * n1 + w4.z * n2 + w4.w * n3;
            }
        }
        #pragma unroll
        for (int tt = 0; tt < 32; ++tt)
            out[(size_t)(t0 + tt) * 512 + 256 + c] = acc[tt];
    }
}

extern "C" void kernel_launch(void* const* d_in, const int* in_sizes, int n_in,
                              void* d_out, int out_size, void* d_ws, size_t ws_size,
                              hipStream_t stream) {
    const float* q   = (const float*)d_in[0];   // (T, C)
    const float* mem = (const float*)d_in[1];   // (M, C)
    const float* U_w = (const float*)d_in[2];
    const float* U_b = (const float*)d_in[3];
    const float* W_w = (const float*)d_in[4];
    const float* W_b = (const float*)d_in[5];

    float* out     = (float*)d_out;                       // (T, 512)
    float* attn    = out + (size_t)T_TOT * 2 * C_DIM;     // (T, 128)
    float* new_mem = attn + (size_t)T_TOT * M_DIM;        // (M, 256)

    float* S       = (float*)d_ws;                        // (M, T) scores, 33.5MB
    float* add_mem = S + (size_t)M_DIM * T_TOT;           // (M, C)

    k_scores_u<<<T_TOT / 32, 256, 0, stream>>>(q, mem, S);
    k_update<<<M_DIM, 256, 0, stream>>>(S, q, add_mem);
    k_gate<<<M_DIM, 256, 0, stream>>>(mem, add_mem, U_w, U_b, W_w, W_b, new_mem);
    k_read<<<T_TOT / 32, 256, 0, stream>>>(q, new_mem, out, attn);
}

// Round 2
// 482.652 us; speedup vs baseline: 1.7005x; 1.7005x over previous
//
#include <hip/hip_runtime.h>
#include <math.h>

#define T_TOT 65536   // N*L
#define C_DIM 256
#define M_DIM 128
#define SHRINKF 0.0025f
#define EPSF 1e-12f

typedef __attribute__((ext_vector_type(8))) short bf8;
typedef __attribute__((ext_vector_type(4))) float f32x4;

// monotonic float<->uint encoding for atomicMax over signed floats
__device__ inline unsigned encf(float f) {
    int i = __float_as_int(f);
    return (i >= 0) ? ((unsigned)i | 0x80000000u) : ~((unsigned)i);
}
__device__ inline float decf(unsigned u) {
    int i = (u & 0x80000000u) ? (int)(u & 0x7fffffffu) : (int)~u;
    return __int_as_float(i);
}

// pack 8 f32 -> 8 bf16 (truncation) via v_perm: 1 instr per 2 elements
__device__ inline bf8 pack_bf8(float4 a, float4 b) {
    union { unsigned i[4]; bf8 v; } u;
    u.i[0] = __builtin_amdgcn_perm(__float_as_uint(a.y), __float_as_uint(a.x), 0x07060302u);
    u.i[1] = __builtin_amdgcn_perm(__float_as_uint(a.w), __float_as_uint(a.z), 0x07060302u);
    u.i[2] = __builtin_amdgcn_perm(__float_as_uint(b.y), __float_as_uint(b.x), 0x07060302u);
    u.i[3] = __builtin_amdgcn_perm(__float_as_uint(b.w), __float_as_uint(b.z), 0x07060302u);
    return u.v;
}

__device__ inline float bredSum(float v, volatile float* red, int tid) {
    #pragma unroll
    for (int o = 32; o > 0; o >>= 1) v += __shfl_down(v, o, 64);
    __syncthreads();
    if ((tid & 63) == 0) red[tid >> 6] = v;
    __syncthreads();
    return red[0] + red[1] + red[2] + red[3];
}

// ---------------- k_prep: q passthrough to out[:, :256], mem->bf16, init ----
__global__ __launch_bounds__(256) void k_prep(const float* __restrict__ q,
                                              const float* __restrict__ mem,
                                              float* __restrict__ out,
                                              short* __restrict__ mem_bf,
                                              unsigned* __restrict__ mx_u,
                                              float* __restrict__ Zf) {
    int tid = threadIdx.x, bid = blockIdx.x;
    const float4* q4 = (const float4*)q;
    float4* o4 = (float4*)out;
    #pragma unroll
    for (int j = 0; j < 4; ++j) {
        int i = bid * 1024 + j * 256 + tid;     // over T*64 float4s
        int t = i >> 6, c4 = i & 63;
        o4[t * 128 + c4] = q4[i];
    }
    if (bid == 0 && tid < 128) { mx_u[tid] = 0u; Zf[tid] = 0.f; }
    if (bid == 1) {
        for (int i = tid; i < M_DIM * C_DIM; i += 256)
            mem_bf[i] = (short)(__float_as_uint(mem[i]) >> 16);
    }
}

// ---------------- K1: S[m,t] = mem @ q^T via MFMA + per-m rowmax atomics ----
// grid = T/64, 256 threads (4 waves). Wave w: m-stripe [w*32, w*32+32).
__global__ __launch_bounds__(256) void k_scores_u(const float* __restrict__ q,
                                                  const short* __restrict__ mem_bf,
                                                  float* __restrict__ S,
                                                  unsigned* __restrict__ mx_u) {
    int tid = threadIdx.x;
    int lane = tid & 63, w = tid >> 6;
    int l15 = lane & 15, quad = lane >> 4;
    int t0 = blockIdx.x * 64;

    f32x4 acc[2][4];
    #pragma unroll
    for (int mt = 0; mt < 2; ++mt)
        #pragma unroll
        for (int tt = 0; tt < 4; ++tt) acc[mt][tt] = (f32x4){0.f, 0.f, 0.f, 0.f};

    #pragma unroll
    for (int ks = 0; ks < 8; ++ks) {
        int k0 = ks * 32 + quad * 8;
        bf8 a[2], b[4];
        #pragma unroll
        for (int mt = 0; mt < 2; ++mt) {
            int m = w * 32 + mt * 16 + l15;
            a[mt] = *(const bf8*)(mem_bf + m * C_DIM + k0);
        }
        #pragma unroll
        for (int tt = 0; tt < 4; ++tt) {
            int t = t0 + tt * 16 + l15;
            const float4* qr = (const float4*)(q + (size_t)t * C_DIM + k0);
            b[tt] = pack_bf8(qr[0], qr[1]);
        }
        #pragma unroll
        for (int mt = 0; mt < 2; ++mt)
            #pragma unroll
            for (int tt = 0; tt < 4; ++tt)
                acc[mt][tt] = __builtin_amdgcn_mfma_f32_16x16x32_bf16(a[mt], b[tt], acc[mt][tt], 0, 0, 0);
    }

    // epilogue: store S (C layout: row m = quad*4+r, col t = l15) + row max
    #pragma unroll
    for (int mt = 0; mt < 2; ++mt) {
        #pragma unroll
        for (int r = 0; r < 4; ++r) {
            int m = w * 32 + mt * 16 + quad * 4 + r;
            float mv = -3e38f;
            #pragma unroll
            for (int tt = 0; tt < 4; ++tt) {
                float v = acc[mt][tt][r];
                S[(size_t)m * T_TOT + t0 + tt * 16 + l15] = v;
                mv = fmaxf(mv, v);
            }
            mv = fmaxf(mv, __shfl_xor(mv, 1, 64));
            mv = fmaxf(mv, __shfl_xor(mv, 2, 64));
            mv = fmaxf(mv, __shfl_xor(mv, 4, 64));
            mv = fmaxf(mv, __shfl_xor(mv, 8, 64));
            if (l15 == 0) atomicMax(mx_u + m, encf(mv));
        }
    }
}

// ---------------- K2a: partial softmax denominators ----------------
// grid = 128m x 8 slices. Z[m] += sum(exp(s - mx)) over slice.
__global__ __launch_bounds__(256) void k_zpart(const float* __restrict__ S,
                                               const unsigned* __restrict__ mx_u,
                                               float* __restrict__ Zf) {
    __shared__ float red[4];
    int m = blockIdx.x >> 3, sl = blockIdx.x & 7, tid = threadIdx.x;
    float mx = decf(mx_u[m]);
    const float4* row4 = (const float4*)(S + (size_t)m * T_TOT + sl * 8192);
    float z = 0.f;
    #pragma unroll
    for (int j = 0; j < 8; ++j) {
        float4 v = row4[j * 256 + tid];
        z += __expf(v.x - mx) + __expf(v.y - mx) + __expf(v.z - mx) + __expf(v.w - mx);
    }
    z = bredSum(z, red, tid);
    if (tid == 0) atomicAdd(Zf + m, z);
}

// ---------------- K2b: survivor compaction + exact f32 gather ----------------
__global__ __launch_bounds__(256) void k_update(const float* __restrict__ S,
                                                const float* __restrict__ q,
                                                const unsigned* __restrict__ mx_u,
                                                const float* __restrict__ Zf,
                                                float* __restrict__ add_mem) {
    __shared__ float red[4];
    __shared__ int   ldsT[2048];
    __shared__ float ldsH[2048];
    __shared__ int   cnt;
    int m = blockIdx.x, tid = threadIdx.x;
    if (tid == 0) cnt = 0;
    float mx = decf(mx_u[m]);
    float invZ = 1.f / Zf[m];
    const float4* row4 = (const float4*)(S + (size_t)m * T_TOT);

    float l1 = 0.f;
    for (int i = tid; i < T_TOT / 4; i += 256) {
        float4 v = row4[i];
        float av[4] = {v.x, v.y, v.z, v.w};
        #pragma unroll
        for (int j = 0; j < 4; ++j) {
            float a = __expf(av[j] - mx) * invZ;
            if (a > SHRINKF) {
                float d = a - SHRINKF;
                float h = d * a / (d + EPSF);
                int p = atomicAdd(&cnt, 1);
                if (p < 2048) { ldsT[p] = i * 4 + j; ldsH[p] = h; }
                l1 += h;
            }
        }
    }
    l1 = bredSum(l1, red, tid);   // barriers publish ldsT/ldsH/cnt
    float invL1 = 1.f / fmaxf(l1, EPSF);

    int n = min(cnt, 2048);
    float acc = 0.f;
    #pragma unroll 4
    for (int j = 0; j < n; ++j)
        acc += ldsH[j] * q[(size_t)ldsT[j] * C_DIM + tid];
    add_mem[m * C_DIM + tid] = acc * invL1;
}

// ---------------- K3: gate + new_mem (+ bf16 copies for MFMA) ----------------
__global__ __launch_bounds__(256) void k_gate(const float* __restrict__ mem,
                                              const float* __restrict__ add_mem,
                                              const float* __restrict__ U_w,
                                              const float* __restrict__ U_b,
                                              const float* __restrict__ W_w,
                                              const float* __restrict__ W_b,
                                              float* __restrict__ new_mem,
                                              short* __restrict__ nm_bf,
                                              short* __restrict__ nmT_bf) {
    __shared__ float ldsM[256], ldsA[256];
    int m = blockIdx.x, c = threadIdx.x;
    ldsM[c] = mem[m * C_DIM + c];
    ldsA[c] = add_mem[m * C_DIM + c];
    __syncthreads();
    float acc = U_b[c] + W_b[c];
    const float4* uw = (const float4*)(U_w + (size_t)c * C_DIM);
    const float4* ww = (const float4*)(W_w + (size_t)c * C_DIM);
    const float4* lm = (const float4*)ldsM;
    const float4* la = (const float4*)ldsA;
    #pragma unroll 8
    for (int k = 0; k < 64; ++k) {
        float4 a = lm[k], u = uw[k];
        acc += a.x * u.x + a.y * u.y + a.z * u.z + a.w * u.w;
        float4 b = la[k], w = ww[k];
        acc += b.x * w.x + b.y * w.y + b.z * w.z + b.w * w.w;
    }
    float g = 1.f / (1.f + __expf(-acc));
    float v = (1.f - g) * ldsM[c] + g * ldsA[c];
    new_mem[m * C_DIM + c] = v;
    short bv = (short)(__float_as_uint(v) >> 16);
    nm_bf[m * C_DIM + c] = bv;
    nmT_bf[c * M_DIM + m] = bv;
}

// ---------------- K4: fused read — MFMA scores, in-reg softmax, MFMA PV -----
// grid = T/64, 256 threads (4 waves). Wave w owns t-rows [w*16, w*16+16).
__global__ __launch_bounds__(256) void k_read(const float* __restrict__ q,
                                              const short* __restrict__ nm_bf,
                                              const short* __restrict__ nmT_bf,
                                              float* __restrict__ out,
                                              float* __restrict__ attn) {
    __shared__ short ldsW[64 * 136];    // W tile bf16, A-layout, +8 pad
    int tid = threadIdx.x;
    int lane = tid & 63, w = tid >> 6;
    int l15 = lane & 15, quad = lane >> 4;
    int t0 = blockIdx.x * 64;
    int tA = t0 + w * 16;

    // phase A: Sc[16t x 128m] = q @ nm^T
    f32x4 sc[8];
    #pragma unroll
    for (int mt = 0; mt < 8; ++mt) sc[mt] = (f32x4){0.f, 0.f, 0.f, 0.f};
    #pragma unroll
    for (int ks = 0; ks < 8; ++ks) {
        int k0 = ks * 32 + quad * 8;
        const float4* qr = (const float4*)(q + (size_t)(tA + l15) * C_DIM + k0);
        bf8 a = pack_bf8(qr[0], qr[1]);
        #pragma unroll
        for (int mt = 0; mt < 8; ++mt) {
            bf8 b = *(const bf8*)(nm_bf + (mt * 16 + l15) * C_DIM + k0);
            sc[mt] = __builtin_amdgcn_mfma_f32_16x16x32_bf16(a, b, sc[mt], 0, 0, 0);
        }
    }

    // phase B: per-row softmax + hard-shrink + L1 norm, all in registers.
    // row t = tA + quad*4 + r lives in 16 lanes (l15) x 8 regs (mt).
    #pragma unroll
    for (int r = 0; r < 4; ++r) {
        float mx = -3e38f;
        #pragma unroll
        for (int mt = 0; mt < 8; ++mt) mx = fmaxf(mx, sc[mt][r]);
        mx = fmaxf(mx, __shfl_xor(mx, 1, 64));
        mx = fmaxf(mx, __shfl_xor(mx, 2, 64));
        mx = fmaxf(mx, __shfl_xor(mx, 4, 64));
        mx = fmaxf(mx, __shfl_xor(mx, 8, 64));
        float z = 0.f;
        #pragma unroll
        for (int mt = 0; mt < 8; ++mt) z += __expf(sc[mt][r] - mx);
        z += __shfl_xor(z, 1, 64); z += __shfl_xor(z, 2, 64);
        z += __shfl_xor(z, 4, 64); z += __shfl_xor(z, 8, 64);
        float invZ = 1.f / z;
        float l1 = 0.f;
        #pragma unroll
        for (int mt = 0; mt < 8; ++mt) {
            float a = __expf(sc[mt][r] - mx) * invZ;
            float d = a - SHRINKF;
            float h = d > 0.f ? d * a / (d + EPSF) : 0.f;
            sc[mt][r] = h;
            l1 += h;
        }
        l1 += __shfl_xor(l1, 1, 64); l1 += __shfl_xor(l1, 2, 64);
        l1 += __shfl_xor(l1, 4, 64); l1 += __shfl_xor(l1, 8, 64);
        float invL1 = 1.f / fmaxf(l1, EPSF);
        int t = tA + quad * 4 + r;
        int tl = w * 16 + quad * 4 + r;
        #pragma unroll
        for (int mt = 0; mt < 8; ++mt) {
            float wv = sc[mt][r] * invL1;
            attn[(size_t)t * M_DIM + mt * 16 + l15] = wv;
            ldsW[tl * 136 + mt * 16 + l15] = (short)(__float_as_uint(wv) >> 16);
        }
    }
    __syncthreads();

    // phase C: PV[16t x 256c] = W @ nm  (K = 128)
    f32x4 pv[16];
    #pragma unroll
    for (int ct = 0; ct < 16; ++ct) pv[ct] = (f32x4){0.f, 0.f, 0.f, 0.f};
    #pragma unroll
    for (int ks = 0; ks < 4; ++ks) {
        int k0 = ks * 32 + quad * 8;
        bf8 a = *(const bf8*)(ldsW + (w * 16 + l15) * 136 + k0);
        #pragma unroll
        for (int ct = 0; ct < 16; ++ct) {
            bf8 b = *(const bf8*)(nmT_bf + (ct * 16 + l15) * M_DIM + k0);
            pv[ct] = __builtin_amdgcn_mfma_f32_16x16x32_bf16(a, b, pv[ct], 0, 0, 0);
        }
    }
    #pragma unroll
    for (int ct = 0; ct < 16; ++ct) {
        #pragma unroll
        for (int r = 0; r < 4; ++r) {
            int t = tA + quad * 4 + r;
            out[(size_t)t * 512 + 256 + ct * 16 + l15] = pv[ct][r];
        }
    }
}

extern "C" void kernel_launch(void* const* d_in, const int* in_sizes, int n_in,
                              void* d_out, int out_size, void* d_ws, size_t ws_size,
                              hipStream_t stream) {
    const float* q   = (const float*)d_in[0];
    const float* mem = (const float*)d_in[1];
    const float* U_w = (const float*)d_in[2];
    const float* U_b = (const float*)d_in[3];
    const float* W_w = (const float*)d_in[4];
    const float* W_b = (const float*)d_in[5];

    float* out     = (float*)d_out;                     // (T, 512)
    float* attn    = out + (size_t)T_TOT * 2 * C_DIM;   // (T, 128)
    float* new_mem = attn + (size_t)T_TOT * M_DIM;      // (M, 256)

    char* ws = (char*)d_ws;
    float*    S       = (float*)ws;                               ws += (size_t)M_DIM * T_TOT * 4;  // 33.5 MB
    unsigned* mx_u    = (unsigned*)ws;                            ws += 512;
    float*    Zf      = (float*)ws;                               ws += 512;
    float*    add_mem = (float*)ws;                               ws += M_DIM * C_DIM * 4;
    short*    mem_bf  = (short*)ws;                               ws += M_DIM * C_DIM * 2;
    short*    nm_bf   = (short*)ws;                               ws += M_DIM * C_DIM * 2;
    short*    nmT_bf  = (short*)ws;                               ws += M_DIM * C_DIM * 2;

    k_prep<<<4096, 256, 0, stream>>>(q, mem, out, mem_bf, mx_u, Zf);
    k_scores_u<<<T_TOT / 64, 256, 0, stream>>>(q, mem_bf, S, mx_u);
    k_zpart<<<M_DIM * 8, 256, 0, stream>>>(S, mx_u, Zf);
    k_update<<<M_DIM, 256, 0, stream>>>(S, q, mx_u, Zf, add_mem);
    k_gate<<<M_DIM, 256, 0, stream>>>(mem, add_mem, U_w, U_b, W_w, W_b, new_mem, nm_bf, nmT_bf);
    k_read<<<T_TOT / 64, 256, 0, stream>>>(q, nm_bf, nmT_bf, out, attn);
}

// Round 3
// 385.534 us; speedup vs baseline: 2.1288x; 1.2519x over previous
//
#include <hip/hip_runtime.h>
#include <math.h>

#define T_TOT 65536   // N*L
#define C_DIM 256
#define M_DIM 128
#define NBLK  1024    // T_TOT/64 score blocks
#define SHRINKF 0.0025f
#define EPSF 1e-12f

typedef __attribute__((ext_vector_type(8))) short bf8;
typedef __attribute__((ext_vector_type(4))) float f32x4;

__device__ inline unsigned pack2(float lo, float hi) {
    // two f32 -> two bf16 (truncation), lo in low half
    return __builtin_amdgcn_perm(__float_as_uint(hi), __float_as_uint(lo), 0x07060302u);
}
__device__ inline float b2f(short s) {
    return __uint_as_float(((unsigned)(unsigned short)s) << 16);
}

// ---------------- k_prep: out[:, :256] = q; q->bf16; mem->bf16; zero accs ----
__global__ __launch_bounds__(256) void k_prep(const float* __restrict__ q,
                                              const float* __restrict__ mem,
                                              float* __restrict__ out,
                                              short* __restrict__ q_bf,
                                              short* __restrict__ mem_bf,
                                              float* __restrict__ add_acc,
                                              float* __restrict__ l1g) {
    int tid = threadIdx.x, bid = blockIdx.x;
    const float4* q4 = (const float4*)q;
    float4* o4 = (float4*)out;
    uint2* qb = (uint2*)q_bf;
    #pragma unroll
    for (int j = 0; j < 8; ++j) {
        int i = bid * 2048 + j * 256 + tid;     // over T*64 float4s
        float4 v = q4[i];
        int t = i >> 6, c4 = i & 63;
        o4[t * 128 + c4] = v;
        qb[i] = make_uint2(pack2(v.x, v.y), pack2(v.z, v.w));
    }
    if (bid == 0) {
        float4* aa = (float4*)add_acc;
        #pragma unroll
        for (int k = 0; k < 32; ++k) aa[k * 256 + tid] = (float4){0.f, 0.f, 0.f, 0.f};
        if (tid < 128) l1g[tid] = 0.f;
    }
    if (bid == 1) {
        for (int i = tid; i < M_DIM * C_DIM; i += 256)
            mem_bf[i] = (short)(__float_as_uint(mem[i]) >> 16);
    }
}

// ---------------- K1: scores mem@q^T -> online (mx, z) partials per block ----
// grid = 1024 (64 t each), 4 waves; wave w: t-tile [bid*64+w*16, +16), all 128 m.
__global__ __launch_bounds__(256) void k_scores_u(const short* __restrict__ q_bf,
                                                  const short* __restrict__ mem_bf,
                                                  float2* __restrict__ partials) {
    __shared__ float lds_mx[4][128];
    __shared__ float lds_z[4][128];
    int tid = threadIdx.x;
    int lane = tid & 63, w = tid >> 6;
    int l15 = lane & 15, quad = lane >> 4;
    int t0 = blockIdx.x * 64 + w * 16;

    f32x4 acc[8];
    #pragma unroll
    for (int mt = 0; mt < 8; ++mt) acc[mt] = (f32x4){0.f, 0.f, 0.f, 0.f};

    const bf8* qrow = (const bf8*)(q_bf + (size_t)(t0 + l15) * C_DIM);
    #pragma unroll
    for (int ks = 0; ks < 8; ++ks) {
        int k0 = ks * 32 + quad * 8;
        bf8 b = *(const bf8*)((const short*)qrow + k0);
        #pragma unroll
        for (int mt = 0; mt < 8; ++mt) {
            bf8 a = *(const bf8*)(mem_bf + (mt * 16 + l15) * C_DIM + k0);
            acc[mt] = __builtin_amdgcn_mfma_f32_16x16x32_bf16(a, b, acc[mt], 0, 0, 0);
        }
    }

    // online (mx, z) per m-row over this wave's 16 t columns
    #pragma unroll
    for (int mt = 0; mt < 8; ++mt) {
        #pragma unroll
        for (int r = 0; r < 4; ++r) {
            int m = mt * 16 + quad * 4 + r;
            float s = acc[mt][r];
            float mx = s;
            mx = fmaxf(mx, __shfl_xor(mx, 1, 64));
            mx = fmaxf(mx, __shfl_xor(mx, 2, 64));
            mx = fmaxf(mx, __shfl_xor(mx, 4, 64));
            mx = fmaxf(mx, __shfl_xor(mx, 8, 64));
            float z = __expf(s - mx);
            z += __shfl_xor(z, 1, 64); z += __shfl_xor(z, 2, 64);
            z += __shfl_xor(z, 4, 64); z += __shfl_xor(z, 8, 64);
            if (l15 == 0) { lds_mx[w][m] = mx; lds_z[w][m] = z; }
        }
    }
    __syncthreads();
    if (tid < 128) {
        int m = tid;
        float mx = lds_mx[0][m], z = lds_z[0][m];
        #pragma unroll
        for (int j = 1; j < 4; ++j) {
            float m2 = lds_mx[j][m], z2 = lds_z[j][m];
            float nm_ = fmaxf(mx, m2);
            z = z * __expf(mx - nm_) + z2 * __expf(m2 - nm_);
            mx = nm_;
        }
        partials[(size_t)blockIdx.x * M_DIM + m] = make_float2(mx, z);
    }
}

// ---------------- K2: reduce partials -> mx, Z, survivor threshold ----------
__global__ __launch_bounds__(256) void k_reduce(const float2* __restrict__ partials,
                                                float4* __restrict__ mxZ) {
    __shared__ float smx[256], sz[256];
    int m = blockIdx.x, tid = threadIdx.x;
    float mx = -3e38f, z = 0.f;
    for (int i = tid; i < NBLK; i += 256) {
        float2 p = partials[(size_t)i * M_DIM + m];
        float nm_ = fmaxf(mx, p.x);
        z = z * __expf(mx - nm_) + p.y * __expf(p.x - nm_);
        mx = nm_;
    }
    smx[tid] = mx; sz[tid] = z;
    __syncthreads();
    for (int s = 128; s > 0; s >>= 1) {
        if (tid < s) {
            float m2 = smx[tid + s], z2 = sz[tid + s];
            float nm_ = fmaxf(smx[tid], m2);
            sz[tid] = sz[tid] * __expf(smx[tid] - nm_) + z2 * __expf(m2 - nm_);
            smx[tid] = nm_;
        }
        __syncthreads();
    }
    if (tid == 0) {
        float Z = sz[0], M = smx[0];
        mxZ[m] = make_float4(M, Z, M + logf(SHRINKF * Z), 1.f / Z);
    }
}

// ---------------- K3: survivor scan (expected zero hits) ----------
// grid = 1024 t-blocks; flag m-rows whose block max beats the threshold,
// recompute their scores and gather exact-f32 q rows via atomics.
__global__ __launch_bounds__(256) void k_survivor(const float2* __restrict__ partials,
                                                  const float4* __restrict__ mxZ,
                                                  const short* __restrict__ q_bf,
                                                  const short* __restrict__ mem_bf,
                                                  const float* __restrict__ q,
                                                  float* __restrict__ add_acc,
                                                  float* __restrict__ l1g) {
    __shared__ int flags[128];
    __shared__ int fcnt;
    __shared__ float ps[256];
    __shared__ float hs[64];
    int tid = threadIdx.x, bid = blockIdx.x;
    if (tid == 0) fcnt = 0;
    __syncthreads();
    if (tid < 128) {
        float2 p = partials[(size_t)bid * M_DIM + tid];
        if (p.x > mxZ[tid].z) { int pos = atomicAdd(&fcnt, 1); flags[pos] = tid; }
    }
    __syncthreads();
    int n = fcnt;
    if (n == 0) return;
    int t0 = bid * 64;
    for (int f = 0; f < n; ++f) {
        int m = flags[f];
        float mx = mxZ[m].x, invZ = mxZ[m].w;
        // scores for 64 t: thread = (t, quarter-of-K)
        int t = tid >> 2, seg = tid & 3;
        float p = 0.f;
        for (int k = seg * 64; k < seg * 64 + 64; ++k)
            p += b2f(mem_bf[m * C_DIM + k]) * b2f(q_bf[(size_t)(t0 + t) * C_DIM + k]);
        ps[t * 4 + seg] = p;
        __syncthreads();
        if (tid < 64) {
            float s = ps[tid * 4] + ps[tid * 4 + 1] + ps[tid * 4 + 2] + ps[tid * 4 + 3];
            float a = __expf(s - mx) * invZ;
            float d = a - SHRINKF;
            hs[tid] = d > 0.f ? d * a / (d + EPSF) : 0.f;
        }
        __syncthreads();
        if (tid == 0) {
            float l1 = 0.f;
            for (int j = 0; j < 64; ++j) l1 += hs[j];
            if (l1 > 0.f) atomicAdd(l1g + m, l1);
        }
        float acc = 0.f;
        bool any = false;
        for (int j = 0; j < 64; ++j) {
            float h = hs[j];
            if (h != 0.f) { acc += h * q[(size_t)(t0 + j) * C_DIM + tid]; any = true; }
        }
        if (any) atomicAdd(add_acc + m * C_DIM + tid, acc);
        __syncthreads();
    }
}

// ---------------- K4: gate + new_mem (+ bf16 copies) ----------------
__global__ __launch_bounds__(256) void k_gate(const float* __restrict__ mem,
                                              const float* __restrict__ add_acc,
                                              const float* __restrict__ l1g,
                                              const float* __restrict__ U_w,
                                              const float* __restrict__ U_b,
                                              const float* __restrict__ W_w,
                                              const float* __restrict__ W_b,
                                              float* __restrict__ new_mem,
                                              short* __restrict__ nm_bf,
                                              short* __restrict__ nmT_bf) {
    __shared__ float ldsM[256], ldsA[256];
    int m = blockIdx.x, c = threadIdx.x;
    ldsM[c] = mem[m * C_DIM + c];
    ldsA[c] = add_acc[m * C_DIM + c] / fmaxf(l1g[m], EPSF);
    __syncthreads();
    float acc = U_b[c] + W_b[c];
    const float4* uw = (const float4*)(U_w + (size_t)c * C_DIM);
    const float4* ww = (const float4*)(W_w + (size_t)c * C_DIM);
    const float4* lm = (const float4*)ldsM;
    const float4* la = (const float4*)ldsA;
    #pragma unroll 8
    for (int k = 0; k < 64; ++k) {
        float4 a = lm[k], u = uw[k];
        acc += a.x * u.x + a.y * u.y + a.z * u.z + a.w * u.w;
        float4 b = la[k], w = ww[k];
        acc += b.x * w.x + b.y * w.y + b.z * w.z + b.w * w.w;
    }
    float g = 1.f / (1.f + __expf(-acc));
    float v = (1.f - g) * ldsM[c] + g * ldsA[c];
    new_mem[m * C_DIM + c] = v;
    short bv = (short)(__float_as_uint(v) >> 16);
    nm_bf[m * C_DIM + c] = bv;
    nmT_bf[c * M_DIM + m] = bv;
}

// ---------------- K5: fused read — MFMA scores, in-reg softmax, MFMA PV -----
__global__ __launch_bounds__(256) void k_read(const short* __restrict__ q_bf,
                                              const short* __restrict__ nm_bf,
                                              const short* __restrict__ nmT_bf,
                                              float* __restrict__ out,
                                              float* __restrict__ attn) {
    __shared__ short ldsW[64 * 136];    // W tile bf16, A-layout, +8 pad
    int tid = threadIdx.x;
    int lane = tid & 63, w = tid >> 6;
    int l15 = lane & 15, quad = lane >> 4;
    int t0 = blockIdx.x * 64;
    int tA = t0 + w * 16;

    // phase A: Sc[16t x 128m] = q @ nm^T
    f32x4 sc[8];
    #pragma unroll
    for (int mt = 0; mt < 8; ++mt) sc[mt] = (f32x4){0.f, 0.f, 0.f, 0.f};
    #pragma unroll
    for (int ks = 0; ks < 8; ++ks) {
        int k0 = ks * 32 + quad * 8;
        bf8 a = *(const bf8*)(q_bf + (size_t)(tA + l15) * C_DIM + k0);
        #pragma unroll
        for (int mt = 0; mt < 8; ++mt) {
            bf8 b = *(const bf8*)(nm_bf + (mt * 16 + l15) * C_DIM + k0);
            sc[mt] = __builtin_amdgcn_mfma_f32_16x16x32_bf16(a, b, sc[mt], 0, 0, 0);
        }
    }

    // phase B: per-row softmax + hard-shrink + L1 norm in registers
    #pragma unroll
    for (int r = 0; r < 4; ++r) {
        float mx = -3e38f;
        #pragma unroll
        for (int mt = 0; mt < 8; ++mt) mx = fmaxf(mx, sc[mt][r]);
        mx = fmaxf(mx, __shfl_xor(mx, 1, 64));
        mx = fmaxf(mx, __shfl_xor(mx, 2, 64));
        mx = fmaxf(mx, __shfl_xor(mx, 4, 64));
        mx = fmaxf(mx, __shfl_xor(mx, 8, 64));
        float z = 0.f;
        #pragma unroll
        for (int mt = 0; mt < 8; ++mt) z += __expf(sc[mt][r] - mx);
        z += __shfl_xor(z, 1, 64); z += __shfl_xor(z, 2, 64);
        z += __shfl_xor(z, 4, 64); z += __shfl_xor(z, 8, 64);
        float invZ = 1.f / z;
        float l1 = 0.f;
        #pragma unroll
        for (int mt = 0; mt < 8; ++mt) {
            float a = __expf(sc[mt][r] - mx) * invZ;
            float d = a - SHRINKF;
            float h = d > 0.f ? d * a / (d + EPSF) : 0.f;
            sc[mt][r] = h;
            l1 += h;
        }
        l1 += __shfl_xor(l1, 1, 64); l1 += __shfl_xor(l1, 2, 64);
        l1 += __shfl_xor(l1, 4, 64); l1 += __shfl_xor(l1, 8, 64);
        float invL1 = 1.f / fmaxf(l1, EPSF);
        int t = tA + quad * 4 + r;
        int tl = w * 16 + quad * 4 + r;
        #pragma unroll
        for (int mt = 0; mt < 8; ++mt) {
            float wv = sc[mt][r] * invL1;
            attn[(size_t)t * M_DIM + mt * 16 + l15] = wv;
            ldsW[tl * 136 + mt * 16 + l15] = (short)(__float_as_uint(wv) >> 16);
        }
    }
    __syncthreads();

    // phase C: PV[16t x 256c] = W @ nm  (K = 128)
    f32x4 pv[16];
    #pragma unroll
    for (int ct = 0; ct < 16; ++ct) pv[ct] = (f32x4){0.f, 0.f, 0.f, 0.f};
    #pragma unroll
    for (int ks = 0; ks < 4; ++ks) {
        int k0 = ks * 32 + quad * 8;
        bf8 a = *(const bf8*)(ldsW + (w * 16 + l15) * 136 + k0);
        #pragma unroll
        for (int ct = 0; ct < 16; ++ct) {
            bf8 b = *(const bf8*)(nmT_bf + (ct * 16 + l15) * M_DIM + k0);
            pv[ct] = __builtin_amdgcn_mfma_f32_16x16x32_bf16(a, b, pv[ct], 0, 0, 0);
        }
    }
    #pragma unroll
    for (int ct = 0; ct < 16; ++ct) {
        #pragma unroll
        for (int r = 0; r < 4; ++r) {
            int t = tA + quad * 4 + r;
            out[(size_t)t * 512 + 256 + ct * 16 + l15] = pv[ct][r];
        }
    }
}

extern "C" void kernel_launch(void* const* d_in, const int* in_sizes, int n_in,
                              void* d_out, int out_size, void* d_ws, size_t ws_size,
                              hipStream_t stream) {
    const float* q   = (const float*)d_in[0];
    const float* mem = (const float*)d_in[1];
    const float* U_w = (const float*)d_in[2];
    const float* U_b = (const float*)d_in[3];
    const float* W_w = (const float*)d_in[4];
    const float* W_b = (const float*)d_in[5];

    float* out     = (float*)d_out;                     // (T, 512)
    float* attn    = out + (size_t)T_TOT * 2 * C_DIM;   // (T, 128)
    float* new_mem = attn + (size_t)T_TOT * M_DIM;      // (M, 256)

    char* ws = (char*)d_ws;
    short*  q_bf     = (short*)ws;    ws += (size_t)T_TOT * C_DIM * 2;   // 33.55 MB
    short*  mem_bf   = (short*)ws;    ws += M_DIM * C_DIM * 2;
    short*  nm_bf    = (short*)ws;    ws += M_DIM * C_DIM * 2;
    short*  nmT_bf   = (short*)ws;    ws += M_DIM * C_DIM * 2;
    float2* partials = (float2*)ws;   ws += (size_t)NBLK * M_DIM * 8;    // 1 MB
    float4* mxZ      = (float4*)ws;   ws += M_DIM * 16;
    float*  add_acc  = (float*)ws;    ws += M_DIM * C_DIM * 4;
    float*  l1g      = (float*)ws;    ws += 512;

    k_prep<<<2048, 256, 0, stream>>>(q, mem, out, q_bf, mem_bf, add_acc, l1g);
    k_scores_u<<<NBLK, 256, 0, stream>>>(q_bf, mem_bf, partials);
    k_reduce<<<M_DIM, 256, 0, stream>>>(partials, mxZ);
    k_survivor<<<NBLK, 256, 0, stream>>>(partials, mxZ, q_bf, mem_bf, q, add_acc, l1g);
    k_gate<<<M_DIM, 256, 0, stream>>>(mem, add_acc, l1g, U_w, U_b, W_w, W_b, new_mem, nm_bf, nmT_bf);
    k_read<<<NBLK, 256, 0, stream>>>(q_bf, nm_bf, nmT_bf, out, attn);
}